// Round 17
// baseline (46.724 us; speedup 1.0000x reference)
//
#include <hip/hip_runtime.h>

// B=4, LQ=256, LK=512, DQ=DK=DV=256, H=128
#define B_   4
#define LQ_  256
#define LK_  512
#define DQK_ 256
#define DV_  256
#define H_   128

#define TANH_C 2.8853900817779268f   // 2*log2(e): tanh(x) = 1 - 2/(exp2(TANH_C*x)+1)
#define L2E    1.4426950408889634f
#define NQBLK (B_ * LQ_ / 4)         // 256 q-proj blocks (TILE=4)
#define NKBLK (B_ * LK_ / 4)         // 512 k-proj blocks

// R17: (1) proj stores eq/ekT with AGENT-scope (write-through) stores so the
// 12MB rewritten every replay lands CLEAN in L3 — attn's cross-XCD re-reads
// are then L3 hits instead of remote-dirty L2 forwards (the R10-measured
// ~13us cold excess; nt-store try was neutral because nt != write-through).
// (2) attn phase B uses float4 LDS reads: 80 ds_read_b32 -> 20 ds_read_b128
// per thread (~2us off the 12us warm floor). attn otherwise R9-exact.

// ---------------------------------------------------------------------------
// proj_kernel: fused q+k projection. TILE=4, 128 threads. Agent-scope stores.
// ---------------------------------------------------------------------------
__global__ __launch_bounds__(128) void proj_kernel(const float* __restrict__ Q,
                                                   const float* __restrict__ K,
                                                   const float* __restrict__ Wq,
                                                   const float* __restrict__ Wk,
                                                   float* __restrict__ eq,
                                                   float* __restrict__ ekT) {
    const int blk = blockIdx.x;
    const bool isq = blk < NQBLK;
    const float* in = isq ? Q  : K;
    const float* W  = isq ? Wq : Wk;
    const int r0 = (isq ? blk : blk - NQBLK) * 4;
    const int t  = threadIdx.x;

    float acc0 = 0.f, acc1 = 0.f, acc2 = 0.f, acc3 = 0.f;
    const float4* in4 = reinterpret_cast<const float4*>(in + (size_t)r0 * DQK_);
    for (int d4 = 0; d4 < DQK_ / 4; ++d4) {
        float4 r0v = in4[0 * (DQK_ / 4) + d4];   // uniform -> s_load
        float4 r1v = in4[1 * (DQK_ / 4) + d4];
        float4 r2v = in4[2 * (DQK_ / 4) + d4];
        float4 r3v = in4[3 * (DQK_ / 4) + d4];
#pragma unroll
        for (int e = 0; e < 4; ++e) {
            float w = W[(size_t)(4 * d4 + e) * H_ + t];   // coalesced
            acc0 = fmaf(reinterpret_cast<const float*>(&r0v)[e], w, acc0);
            acc1 = fmaf(reinterpret_cast<const float*>(&r1v)[e], w, acc1);
            acc2 = fmaf(reinterpret_cast<const float*>(&r2v)[e], w, acc2);
            acc3 = fmaf(reinterpret_cast<const float*>(&r3v)[e], w, acc3);
        }
    }
    float e0 = __builtin_amdgcn_exp2f(acc0 * TANH_C);
    float e1 = __builtin_amdgcn_exp2f(acc1 * TANH_C);
    float e2 = __builtin_amdgcn_exp2f(acc2 * TANH_C);
    float e3 = __builtin_amdgcn_exp2f(acc3 * TANH_C);
    if (isq) {
        __hip_atomic_store(&eq[(size_t)(r0 + 0) * H_ + t], e0, __ATOMIC_RELAXED, __HIP_MEMORY_SCOPE_AGENT);
        __hip_atomic_store(&eq[(size_t)(r0 + 1) * H_ + t], e1, __ATOMIC_RELAXED, __HIP_MEMORY_SCOPE_AGENT);
        __hip_atomic_store(&eq[(size_t)(r0 + 2) * H_ + t], e2, __ATOMIC_RELAXED, __HIP_MEMORY_SCOPE_AGENT);
        __hip_atomic_store(&eq[(size_t)(r0 + 3) * H_ + t], e3, __ATOMIC_RELAXED, __HIP_MEMORY_SCOPE_AGENT);
    } else {
        const int b  = r0 >> 9;
        const int k0 = r0 & (LK_ - 1);
        float* o = ekT + ((size_t)(b * H_ + t)) * LK_ + k0;
        __hip_atomic_store(o + 0, e0, __ATOMIC_RELAXED, __HIP_MEMORY_SCOPE_AGENT);
        __hip_atomic_store(o + 1, e1, __ATOMIC_RELAXED, __HIP_MEMORY_SCOPE_AGENT);
        __hip_atomic_store(o + 2, e2, __ATOMIC_RELAXED, __HIP_MEMORY_SCOPE_AGENT);
        __hip_atomic_store(o + 3, e3, __ATOMIC_RELAXED, __HIP_MEMORY_SCOPE_AGENT);
    }
}

// ---------------------------------------------------------------------------
// attn_kernel (R9 body, phase-B LDS reads vectorized): one block per
// (b, q-tile of 4), 1024 threads (16 waves).
// ---------------------------------------------------------------------------
__global__ __launch_bounds__(1024) void attn_kernel(
    const float* __restrict__ eq,          // [B*LQ, H]
    const float* __restrict__ ekT,         // [B, H, LK]
    const float* __restrict__ wv,          // [H]
    const float* __restrict__ values,      // [B, LK, DV]
    const int*   __restrict__ valid_lens,  // [B]
    float* __restrict__ out) {             // [B*LQ, DV]
    __shared__ float eq_l[4][H_];          // 2 KB
    __shared__ float wm2[H_];              // 512 B
    __shared__ float sc[LK_][4];           // 8 KB (e-values, [k][row])
    __shared__ float scratch[8 * 128 * 20];// 80 KB: partB then partD
    __shared__ float red[16];
    __shared__ float inv_s[4];

    float (*partB)[128][20] = reinterpret_cast<float (*)[128][20]>(scratch);
    float (*partD)[4][DV_]  = reinterpret_cast<float (*)[4][DV_]>(scratch);

    const int blk = blockIdx.x;            // b*64 + qt
    const int b   = blk >> 6;
    const int qt  = blk & 63;
    const int t   = threadIdx.x;

    if (t < 512) {
        eq_l[t >> 7][t & 127] = eq[(size_t)(b * LQ_ + qt * 4 + (t >> 7)) * H_ + (t & 127)];
    } else if (t < 640) {
        wm2[t - 512] = -2.f * wv[t - 512];
    }
    __syncthreads();

    const int valid = valid_lens[b];

    // ---- Phase B: register-blocked partial scores (float4 LDS reads) ----
    {
        const int quad = t & 127;          // k-quad: k = 4*quad + e
        const int hs   = t >> 7;           // h-slice: h = 16*hs + hh
        const int k0   = 4 * quad;
        float acc[16];
#pragma unroll
        for (int i = 0; i < 16; ++i) acc[i] = 0.f;

        if (k0 < valid) {
            const float* ekb = ekT + (size_t)b * H_ * LK_ + k0;
            const float4* wm4 = reinterpret_cast<const float4*>(&wm2[16 * hs]);
            const float4* qa4 = reinterpret_cast<const float4*>(&eq_l[0][16 * hs]);
            const float4* qb4 = reinterpret_cast<const float4*>(&eq_l[1][16 * hs]);
            const float4* qc4 = reinterpret_cast<const float4*>(&eq_l[2][16 * hs]);
            const float4* qd4 = reinterpret_cast<const float4*>(&eq_l[3][16 * hs]);
#pragma unroll
            for (int h4 = 0; h4 < 4; ++h4) {
                float4 wv4 = wm4[h4];      // ds_read_b128
                float4 qa  = qa4[h4];
                float4 qb  = qb4[h4];
                float4 qc  = qc4[h4];
                float4 qd  = qd4[h4];
#pragma unroll
                for (int e = 0; e < 4; ++e) {
                    const int h = 16 * hs + 4 * h4 + e;
                    float4 ek = *reinterpret_cast<const float4*>(ekb + (size_t)h * LK_);
                    const float w  = reinterpret_cast<const float*>(&wv4)[e];
                    const float q0 = reinterpret_cast<const float*>(&qa)[e];
                    const float q1 = reinterpret_cast<const float*>(&qb)[e];
                    const float q2 = reinterpret_cast<const float*>(&qc)[e];
                    const float q3 = reinterpret_cast<const float*>(&qd)[e];
                    acc[0]  = fmaf(w, __builtin_amdgcn_rcpf(fmaf(q0, ek.x, 1.f)), acc[0]);
                    acc[1]  = fmaf(w, __builtin_amdgcn_rcpf(fmaf(q0, ek.y, 1.f)), acc[1]);
                    acc[2]  = fmaf(w, __builtin_amdgcn_rcpf(fmaf(q0, ek.z, 1.f)), acc[2]);
                    acc[3]  = fmaf(w, __builtin_amdgcn_rcpf(fmaf(q0, ek.w, 1.f)), acc[3]);
                    acc[4]  = fmaf(w, __builtin_amdgcn_rcpf(fmaf(q1, ek.x, 1.f)), acc[4]);
                    acc[5]  = fmaf(w, __builtin_amdgcn_rcpf(fmaf(q1, ek.y, 1.f)), acc[5]);
                    acc[6]  = fmaf(w, __builtin_amdgcn_rcpf(fmaf(q1, ek.z, 1.f)), acc[6]);
                    acc[7]  = fmaf(w, __builtin_amdgcn_rcpf(fmaf(q1, ek.w, 1.f)), acc[7]);
                    acc[8]  = fmaf(w, __builtin_amdgcn_rcpf(fmaf(q2, ek.x, 1.f)), acc[8]);
                    acc[9]  = fmaf(w, __builtin_amdgcn_rcpf(fmaf(q2, ek.y, 1.f)), acc[9]);
                    acc[10] = fmaf(w, __builtin_amdgcn_rcpf(fmaf(q2, ek.z, 1.f)), acc[10]);
                    acc[11] = fmaf(w, __builtin_amdgcn_rcpf(fmaf(q2, ek.w, 1.f)), acc[11]);
                    acc[12] = fmaf(w, __builtin_amdgcn_rcpf(fmaf(q3, ek.x, 1.f)), acc[12]);
                    acc[13] = fmaf(w, __builtin_amdgcn_rcpf(fmaf(q3, ek.y, 1.f)), acc[13]);
                    acc[14] = fmaf(w, __builtin_amdgcn_rcpf(fmaf(q3, ek.z, 1.f)), acc[14]);
                    acc[15] = fmaf(w, __builtin_amdgcn_rcpf(fmaf(q3, ek.w, 1.f)), acc[15]);
                }
            }
        }
        float* pb = &partB[hs][quad][0];
#pragma unroll
        for (int i = 0; i < 4; ++i)
            *reinterpret_cast<float4*>(pb + 4 * i) = *reinterpret_cast<float4*>(&acc[4 * i]);
    }
    __syncthreads();

    // ---- Score stage: reduce 8 h-slices, exp2, mask -> sc[k][r] ----
#pragma unroll
    for (int j = 0; j < 2; ++j) {
        const int o    = t + 1024 * j;     // 0..2047
        const int quad = o >> 4;
        const int idx  = o & 15;           // r*4 + e
        const int k    = 4 * quad + (idx & 3);
        float s = 0.f;
#pragma unroll
        for (int hs = 0; hs < 8; ++hs) s += partB[hs][quad][idx];
        sc[k][idx >> 2] = (k < valid) ? __builtin_amdgcn_exp2f(s * L2E) : 0.f;
    }
    __syncthreads();

    // ---- Phase C: per-row sum only (wave w -> row qi = w>>2) ----
    const int qi = t >> 8;                 // 0..3 wave-uniform
    const int kl = t & 255;
    {
        float ss = sc[kl][qi] + sc[kl + 256][qi];
#pragma unroll
        for (int off = 32; off; off >>= 1) ss += __shfl_down(ss, off, 64);
        if ((t & 63) == 0) red[t >> 6] = ss;
    }
    __syncthreads();
    if (t < 4) {
        inv_s[t] = 1.f / (red[4 * t] + red[4 * t + 1] + red[4 * t + 2] + red[4 * t + 3]);
    }
    __syncthreads();                        // also fences partB before partD reuse

    // ---- Phase D: out = attn @ values (float4 values, wave-per-k-slice) ----
    {
        const int w  = __builtin_amdgcn_readfirstlane(t >> 6);  // wave 0..15
        const int v  = 4 * (t & 63);
        const int kstart = 32 * w;
        const int kend   = min(kstart + 32, valid);
        const float* vb = values + (size_t)b * LK_ * DV_ + v;
        float4 a0 = make_float4(0.f, 0.f, 0.f, 0.f);
        float4 a1 = a0, a2 = a0, a3 = a0;
#pragma unroll 2
        for (int k = kstart; k < kend; ++k) {
            float4 sv = *reinterpret_cast<const float4*>(&sc[k][0]);     // broadcast
            float4 vv = *reinterpret_cast<const float4*>(vb + (size_t)k * DV_); // coalesced
            a0.x = fmaf(sv.x, vv.x, a0.x); a0.y = fmaf(sv.x, vv.y, a0.y);
            a0.z = fmaf(sv.x, vv.z, a0.z); a0.w = fmaf(sv.x, vv.w, a0.w);
            a1.x = fmaf(sv.y, vv.x, a1.x); a1.y = fmaf(sv.y, vv.y, a1.y);
            a1.z = fmaf(sv.y, vv.z, a1.z); a1.w = fmaf(sv.y, vv.w, a1.w);
            a2.x = fmaf(sv.z, vv.x, a2.x); a2.y = fmaf(sv.z, vv.y, a2.y);
            a2.z = fmaf(sv.z, vv.z, a2.z); a2.w = fmaf(sv.z, vv.w, a2.w);
            a3.x = fmaf(sv.w, vv.x, a3.x); a3.y = fmaf(sv.w, vv.y, a3.y);
            a3.z = fmaf(sv.w, vv.z, a3.z); a3.w = fmaf(sv.w, vv.w, a3.w);
        }
        *reinterpret_cast<float4*>(&partD[w][0][v]) = a0;
        *reinterpret_cast<float4*>(&partD[w][1][v]) = a1;
        *reinterpret_cast<float4*>(&partD[w][2][v]) = a2;
        *reinterpret_cast<float4*>(&partD[w][3][v]) = a3;
    }
    __syncthreads();
    {
        const int r = t >> 8;
        const int v = t & 255;
        float s = 0.f;
#pragma unroll
        for (int w = 0; w < 16; ++w) s += partD[w][r][v];
        out[(size_t)(b * LQ_ + qt * 4 + r) * DV_ + v] = s * inv_s[r];
    }
}

extern "C" void kernel_launch(void* const* d_in, const int* in_sizes, int n_in,
                              void* d_out, int out_size, void* d_ws, size_t ws_size,
                              hipStream_t stream) {
    const float* queries    = (const float*)d_in[0];  // [B, LQ, DQ]
    const float* keys       = (const float*)d_in[1];  // [B, LK, DK]
    const float* values     = (const float*)d_in[2];  // [B, LK, DV]
    const float* Wq         = (const float*)d_in[3];  // [DQ, H]
    const float* Wk         = (const float*)d_in[4];  // [DK, H]
    const float* wv         = (const float*)d_in[5];  // [H]
    const int*   valid_lens = (const int*)d_in[6];    // [B]
    float* out = (float*)d_out;

    float* eq  = (float*)d_ws;                   // [B*LQ, H]   512 KB
    float* ekT = eq + (size_t)B_ * LQ_ * H_;     // [B, H, LK]  1 MB

    proj_kernel<<<NQBLK + NKBLK, 128, 0, stream>>>(queries, keys, Wq, Wk, eq, ekT);
    attn_kernel<<<B_ * LQ_ / 4, 1024, 0, stream>>>(eq, ekT, wv, values, valid_lens, out);
}